// Round 16
// baseline (167.413 us; speedup 1.0000x reference)
//
#include <hip/hip_runtime.h>
#include <hip/hip_bf16.h>
#include <math.h>

#define BDIM 128   // batch

typedef short sh8 __attribute__((ext_vector_type(8)));
typedef __bf16 bf8 __attribute__((ext_vector_type(8)));
typedef float f32x4 __attribute__((ext_vector_type(4)));

__device__ inline float bf2f(unsigned short u) {
    union { unsigned int i; float f; } v; v.i = ((unsigned int)u) << 16; return v.f;
}
__device__ inline unsigned short f2bf(float f) {
    union { unsigned int i; float f; } v; v.f = f;
    unsigned int x = v.i;
    return (unsigned short)((x + 0x7FFFu + ((x >> 16) & 1u)) >> 16);  // RNE
}

// within-8 ushort XOR shuffle (compile-time folded inside unrolled loops)
__device__ inline sh8 xshuf(sh8 v, int u) {
    switch (u & 7) {
    case 0: return v;
    case 1: return __builtin_shufflevector(v,v,1,0,3,2,5,4,7,6);
    case 2: return __builtin_shufflevector(v,v,2,3,0,1,6,7,4,5);
    case 3: return __builtin_shufflevector(v,v,3,2,1,0,7,6,5,4);
    case 4: return __builtin_shufflevector(v,v,4,5,6,7,0,1,2,3);
    case 5: return __builtin_shufflevector(v,v,5,4,7,6,1,0,3,2);
    case 6: return __builtin_shufflevector(v,v,6,7,4,5,2,3,0,1);
    default: return __builtin_shufflevector(v,v,7,6,5,4,3,2,1,0);
    }
}

// ---- fused encoder: MLP -> A (LDS only) -> P2 -> P4 (bf16, plain+transposed)
// One block per batch b. Also zero-inits norm2[b] and cnt[b].
__global__ __launch_bounds__(256) void enc_fused(
    const float* __restrict__ x,
    const float* __restrict__ W1, const float* __restrict__ b1,
    const float* __restrict__ W2, const float* __restrict__ b2,
    const float* __restrict__ W3, const float* __restrict__ b3,
    unsigned short* __restrict__ P4n, unsigned short* __restrict__ P4t,
    float* __restrict__ nrm, unsigned int* __restrict__ cnt)
{
    __shared__ float h1[1024];
    __shared__ float part[8][33];
    __shared__ float h2[32];
    __shared__ float aT[2][32][36], an[2][32][36];
    __shared__ float p2T[4][32][36], p2n[4][32][36];
    int b = blockIdx.x, t = threadIdx.x;
    if (t == 0) { nrm[b] = 0.f; cnt[b] = 0u; }
    float x0 = x[b*4+0], x1 = x[b*4+1], x2 = x[b*4+2], x3 = x[b*4+3];
#pragma unroll
    for (int q = 0; q < 4; ++q) {
        int j = t + 256*q;
        float4 w = *(const float4*)(W1 + (size_t)j*4);
        float v = x0*w.x + x1*w.y + x2*w.z + x3*w.w + b1[j];
        h1[j] = v > 0.f ? v : 0.f;
    }
    __syncthreads();
    {
        int o = t & 31, chunk = t >> 5;
        const float* w2r = W2 + (size_t)o*1024 + chunk*128;
        const float* h1r = h1 + chunk*128;
        float s = 0.f;
#pragma unroll
        for (int k = 0; k < 128; k += 4) {
            float4 w = *(const float4*)(w2r + k);
            s += h1r[k]*w.x + h1r[k+1]*w.y + h1r[k+2]*w.z + h1r[k+3]*w.w;
        }
        part[chunk][o] = s;
    }
    __syncthreads();
    if (t < 32) {
        float s = b2[t];
#pragma unroll
        for (int c = 0; c < 8; ++c) s += part[c][t];
        h2[t] = s > 0.f ? s : 0.f;
    }
    __syncthreads();
#pragma unroll
    for (int q = 0; q < 8; ++q) {   // e = W3 h2 + b3 -> A matrices in LDS
        int j = t + 256*q;
        const float* w3r = W3 + (size_t)j*32;
        float s = b3[j];
#pragma unroll
        for (int i = 0; i < 32; i += 4) {
            float4 w = *(const float4*)(w3r + i);
            s += h2[i]*w.x + h2[i+1]*w.y + h2[i+2]*w.z + h2[i+3]*w.w;
        }
        int spin = j >> 10, off = j & 1023;
        int row = off >> 5, c = off & 31;
        an[spin][row][c] = s;
        aT[spin][c][row] = s;
    }
    __syncthreads();
    int w = t >> 6, l = t & 63;
    int r0 = (l >> 3) << 2, c0 = (l & 7) << 2;
    {   // P2[w] = A[w>>1] @ A[w&1]
        float acc[4][4] = {};
#pragma unroll 8
        for (int kk = 0; kk < 32; ++kk) {
            float a[4], bb[4];
            *(float4*)a  = *(const float4*)&aT[w>>1][kk][r0];
            *(float4*)bb = *(const float4*)&an[w&1][kk][c0];
#pragma unroll
            for (int i = 0; i < 4; ++i)
#pragma unroll
                for (int j = 0; j < 4; ++j)
                    acc[i][j] += a[i]*bb[j];
        }
#pragma unroll
        for (int i = 0; i < 4; ++i)
#pragma unroll
            for (int j = 0; j < 4; ++j) {
                p2n[w][r0+i][c0+j] = acc[i][j];
                p2T[w][c0+j][r0+i] = acc[i][j];
            }
    }
    __syncthreads();
#pragma unroll
    for (int it = 0; it < 4; ++it) {   // P4[u] = P2[w] @ P2[it], u=(w<<2)|it
        int u = (w << 2) | it;
        float acc[4][4] = {};
#pragma unroll 8
        for (int kk = 0; kk < 32; ++kk) {
            float a[4], bb[4];
            *(float4*)a  = *(const float4*)&p2T[w][kk][r0];
            *(float4*)bb = *(const float4*)&p2n[it][kk][c0];
#pragma unroll
            for (int i = 0; i < 4; ++i)
#pragma unroll
                for (int j = 0; j < 4; ++j)
                    acc[i][j] += a[i]*bb[j];
        }
        unsigned short* dstN = P4n + ((size_t)b*16 + u)*1024;
        unsigned short* dstT = P4t + ((size_t)b*16 + u)*1024;
#pragma unroll
        for (int i = 0; i < 4; ++i) {
            ushort4 v; v.x = f2bf(acc[i][0]); v.y = f2bf(acc[i][1]);
            v.z = f2bf(acc[i][2]); v.w = f2bf(acc[i][3]);
            *(ushort4*)(dstN + (r0+i)*32 + c0) = v;
        }
#pragma unroll
        for (int j = 0; j < 4; ++j) {
            ushort4 v; v.x = f2bf(acc[0][j]); v.y = f2bf(acc[1][j]);
            v.z = f2bf(acc[2][j]); v.w = f2bf(acc[3][j]);
            *(ushort4*)(dstT + (c0+j)*32 + r0) = v;
        }
    }
}

// ---- LL via MFMA: per (b,hi) C(32x512) = P4[hi] @ [P4[0..15]], K=32 -------
__global__ __launch_bounds__(256) void ll_mfma(
    const unsigned short* __restrict__ P4n, const unsigned short* __restrict__ P4t,
    unsigned short* __restrict__ LL)
{
    int hi = blockIdx.x, b = blockIdx.y;
    __shared__ __align__(16) unsigned short As[32][40];
    __shared__ __align__(16) unsigned short Bs[512][40];
    __shared__ __align__(16) unsigned short outst[16][1024];  // 32 KB
    int t = threadIdx.x;
    int w = t >> 6, l = t & 63;
    int lr = l & 15, lg = l >> 4;
    int wn = w * 128;

    {   // stage A (first 128 threads): 32 rows x 4 sh8
        if (t < 128) {
            int i = t >> 2, k8 = (t & 3) * 8;
            *(sh8*)&As[i][k8] = *(const sh8*)(P4n + ((size_t)b*16 + hi)*1024 + i*32 + k8);
        }
        // stage B: 512 rows x 4 sh8 = 2048 sh8
#pragma unroll
        for (int rep = 0; rep < 8; ++rep) {
            int flat = rep*256 + t;
            int n = flat >> 2, k8 = (flat & 3) * 8;
            *(sh8*)&Bs[n][k8] =
                *(const sh8*)(P4t + ((size_t)b*16 + (n >> 5))*1024 + (n & 31)*32 + k8);
        }
    }
    __syncthreads();

    f32x4 acc[2][8] = {};
    bf8 av[2], bv[8];
#pragma unroll
    for (int m = 0; m < 2; ++m)
        av[m] = __builtin_bit_cast(bf8, *(const sh8*)&As[m*16 + lr][lg*8]);
#pragma unroll
    for (int n = 0; n < 8; ++n)
        bv[n] = __builtin_bit_cast(bf8, *(const sh8*)&Bs[wn + n*16 + lr][lg*8]);
#pragma unroll
    for (int m = 0; m < 2; ++m)
#pragma unroll
        for (int n = 0; n < 8; ++n)
            acc[m][n] = __builtin_amdgcn_mfma_f32_16x16x32_bf16(av[m], bv[n], acc[m][n], 0, 0, 0);
    __syncthreads();

    // scatter to XOR-pair layout in LDS
#pragma unroll
    for (int m = 0; m < 2; ++m)
#pragma unroll
        for (int n = 0; n < 8; ++n) {
            f32x4 v = acc[m][n];
            int col = wn + n*16 + lr;
            int qlo = col >> 5, j = col & 31;
#pragma unroll
            for (int r = 0; r < 4; ++r) {
                int i = m*16 + lg*4 + r;
                outst[qlo][((i ^ j) << 5) | j] = f2bf(v[r]);
            }
        }
    __syncthreads();
    unsigned short* dst = LL + ((size_t)b*256 + hi*16)*1024;
    const uint4* s4 = (const uint4*)&outst[0][0];   // 2048 x 16B
    uint4* d4 = (uint4*)dst;
#pragma unroll
    for (int rep = 0; rep < 8; ++rep)
        d4[rep*256 + t] = s4[rep*256 + t];
}

// ---- pairing + fused normalize, symmetric: blocks (0,0),(0,1)+mirror,(1,1).
// Per-batch counter sync: 3 blocks/batch, grid 384 <= 768 co-resident capacity
// (3 blocks/CU by LDS 41KB and VGPR), so the spin cannot deadlock.
__global__ __launch_bounds__(256) void pair_sym(
    const unsigned short* __restrict__ LL,
    float* __restrict__ out, float* __restrict__ norm2,
    unsigned int* __restrict__ cnt)
{
    int b = blockIdx.y;
    int bx = blockIdx.x;
    int ti = (bx >> 1);            // 0,0,1
    int tj = (bx + 1) >> 1;        // 0,1,1
    const unsigned short* Ab = LL + (size_t)b*262144 + (size_t)ti*131072;
    const unsigned short* Bb = LL + (size_t)b*262144 + (size_t)tj*131072;
    __shared__ __align__(16) unsigned short As[2][128][40];
    __shared__ __align__(16) unsigned short Bs[2][128][40];
    __shared__ float wsum[4];
    __shared__ float sfac;
    int t = threadIdx.x;
    int w = t >> 6, l = t & 63;
    int row0 = t >> 2;
    int j8 = (t & 3) * 8;
    int wm = (w >> 1) * 64, wn = (w & 1) * 64;
    int lr = l & 15, lg = l >> 4;

    const unsigned short* Ar0 = Ab + (size_t)row0*1024;
    const unsigned short* Ar1 = Ab + (size_t)(row0+64)*1024;
    const unsigned short* Br0 = Bb + (size_t)row0*1024;
    const unsigned short* Br1 = Bb + (size_t)(row0+64)*1024;

    f32x4 acc[4][4] = {};
    sh8 ra0, ra1, rb0, rb1;

    ra0 = *(const sh8*)(Ar0 + j8);
    ra1 = *(const sh8*)(Ar1 + j8);
    rb0 = *(const sh8*)(Br0 + j8);
    rb1 = *(const sh8*)(Br1 + j8);
    *(sh8*)&As[0][row0][j8]    = ra0;
    *(sh8*)&As[0][row0+64][j8] = ra1;
    *(sh8*)&Bs[0][row0][j8]    = rb0;
    *(sh8*)&Bs[0][row0+64][j8] = rb1;
    __syncthreads();

#pragma unroll
    for (int d = 0; d < 32; ++d) {
        int cur = d & 1, nxt = cur ^ 1;
        int dn = d + 1;
        if (dn < 32) {
            int aoff = dn*32 + j8;
            int boff = dn*32 + (j8 ^ ((dn >> 3) << 3));
            ra0 = *(const sh8*)(Ar0 + aoff);
            ra1 = *(const sh8*)(Ar1 + aoff);
            rb0 = *(const sh8*)(Br0 + boff);
            rb1 = *(const sh8*)(Br1 + boff);
        }
        bf8 av[4], bv[4];
#pragma unroll
        for (int m = 0; m < 4; ++m) {
            av[m] = __builtin_bit_cast(bf8, *(const sh8*)&As[cur][wm + m*16 + lr][lg*8]);
            bv[m] = __builtin_bit_cast(bf8, *(const sh8*)&Bs[cur][wn + m*16 + lr][lg*8]);
        }
#pragma unroll
        for (int m = 0; m < 4; ++m)
#pragma unroll
            for (int n = 0; n < 4; ++n)
                acc[m][n] = __builtin_amdgcn_mfma_f32_16x16x32_bf16(av[m], bv[n], acc[m][n], 0, 0, 0);
        if (dn < 32) {
            int u = dn & 7;
            *(sh8*)&As[nxt][row0][j8]    = ra0;
            *(sh8*)&As[nxt][row0+64][j8] = ra1;
            *(sh8*)&Bs[nxt][row0][j8]    = xshuf(rb0, u);
            *(sh8*)&Bs[nxt][row0+64][j8] = xshuf(rb1, u);
        }
        __syncthreads();
    }

    // partial sum of squares (off-diagonal tile counted twice: mirror block)
    float ss = 0.f;
#pragma unroll
    for (int m = 0; m < 4; ++m)
#pragma unroll
        for (int n = 0; n < 4; ++n) {
            f32x4 v = acc[m][n];
#pragma unroll
            for (int r = 0; r < 4; ++r) ss += v[r]*v[r];
        }
    if (ti != tj) ss *= 2.f;
#pragma unroll
    for (int o = 1; o < 64; o <<= 1) ss += __shfl_xor(ss, o);
    if (l == 0) wsum[w] = ss;
    __syncthreads();
    if (t == 0) {
        atomicAdd(norm2 + b, wsum[0]+wsum[1]+wsum[2]+wsum[3]);
        __threadfence();                       // nrm visible before cnt bump
        atomicAdd(cnt + b, 1u);
        while (atomicAdd(cnt + b, 0u) < 3u) {} // wait for the other 2 blocks
        sfac = rsqrtf(atomicAdd(norm2 + b, 0.f));
    }
    __syncthreads();
    float s = sfac;

    size_t ob = (size_t)b*65536;
#pragma unroll
    for (int m = 0; m < 4; ++m) {
#pragma unroll
        for (int n = 0; n < 4; ++n) {
            f32x4 v = acc[m][n];
            int s0 = ti*128 + wm + m*16 + lg*4;
            int t0 = tj*128 + wn + n*16 + lr;
            float* op = out + ob + (size_t)s0*256 + t0;
#pragma unroll
            for (int r = 0; r < 4; ++r)
                op[r*256] = v[r]*s;
            if (ti != tj) {   // mirror tile (1,0): C[t0][s0..s0+3]
                *(float4*)(out + ob + (size_t)t0*256 + s0) =
                    make_float4(v[0]*s, v[1]*s, v[2]*s, v[3]*s);
            }
        }
    }
}

extern "C" void kernel_launch(void* const* d_in, const int* in_sizes, int n_in,
                              void* d_out, int out_size, void* d_ws, size_t ws_size,
                              hipStream_t stream)
{
    (void)in_sizes; (void)n_in;
    const float* x  = (const float*)d_in[0];
    const float* W1 = (const float*)d_in[1];
    const float* b1 = (const float*)d_in[2];
    const float* W2 = (const float*)d_in[3];
    const float* b2 = (const float*)d_in[4];
    const float* W3 = (const float*)d_in[5];
    const float* b3 = (const float*)d_in[6];
    float* out = (float*)d_out;

    // ---- workspace (peak 72 MB + 1 KB) ----
    char* W = (char*)d_ws;
    const size_t MB = 1024*1024;
    unsigned short* LL  = (unsigned short*)(W + 0);      // bf16 [128][256][1024] 64MB
    unsigned short* P4n = (unsigned short*)(W + 64*MB);  // bf16 [128][16][1024]   4MB
    unsigned short* P4t = (unsigned short*)(W + 68*MB);  // bf16 [128][16][1024]   4MB
    float* nrm = (float*)(W + 72*MB);                    // f32 [128]
    unsigned int* cnt = (unsigned int*)(W + 72*MB + 512);// u32 [128]
    const size_t NEED = 72*MB + 1024;
    if (ws_size < NEED) {
        hipMemsetAsync(d_out, 0, (size_t)out_size * sizeof(float), stream);
        return;
    }

    enc_fused<<<BDIM, 256, 0, stream>>>(x, W1, b1, W2, b2, W3, b3, P4n, P4t, nrm, cnt);
    ll_mfma<<<dim3(16, BDIM), 256, 0, stream>>>(P4n, P4t, LL);
    pair_sym<<<dim3(3, BDIM), 256, 0, stream>>>(LL, out, nrm, cnt);
}